// Round 12
// baseline (475.989 us; speedup 1.0000x reference)
//
#include <hip/hip_runtime.h>
#include <hip/hip_bf16.h>

#define VOCAB 2048
#define EMBD  256
#define LATD  64
#define TLEN  32
#define BATCH 64
#define NBLK  256
#define NCG   128   // column groups (16 vocab cols each); rows split 2-way

typedef __attribute__((ext_vector_type(8))) short bf16x8;
typedef __attribute__((ext_vector_type(4))) float f32x4;

// ---------------- init: h ring slot0 = 0, arrv/rel = 0 ----------------
__global__ void k_init(ushort* __restrict__ h0, unsigned* __restrict__ arrv) {
  int i = blockIdx.x * 256 + threadIdx.x;   // grid 512*256 = 131072
  h0[i] = 0;                                 // 64*2048 bf16 (ring slot 0)
  if (i < 384) arrv[i] = 0;                  // 256 arrv + 128 rel words
}

// ---------- transpose+convert: src[K][8192] f32 -> dst[8192][K] bf16 ----------
__global__ void k_transpose(const float* __restrict__ src,
                            __hip_bfloat16* __restrict__ dst, int K) {
  __shared__ __hip_bfloat16 tile[64][72];
  int k0 = (blockIdx.x >> 7) * 64;
  int n0 = (blockIdx.x & 127) * 64;
  int tid = threadIdx.x;
  {
    int kl = tid >> 2;
    int nq = (tid & 3) << 4;
    const float* s = src + (size_t)(k0 + kl) * 8192 + n0 + nq;
#pragma unroll
    for (int i = 0; i < 4; ++i) {
      float4 v = *reinterpret_cast<const float4*>(s + i * 4);
      tile[nq + i * 4 + 0][kl] = __float2bfloat16(v.x);
      tile[nq + i * 4 + 1][kl] = __float2bfloat16(v.y);
      tile[nq + i * 4 + 2][kl] = __float2bfloat16(v.z);
      tile[nq + i * 4 + 3][kl] = __float2bfloat16(v.w);
    }
  }
  __syncthreads();
  {
    int nl = tid >> 2;
    int kq = (tid & 3) << 4;
    uint4* d = reinterpret_cast<uint4*>(dst + (size_t)(n0 + nl) * K + k0 + kq);
    const uint4* s = reinterpret_cast<const uint4*>(&tile[nl][kq]);
    d[0] = s[0];
    d[1] = s[1];
  }
}

// ---------- gather: xb[t*64+b][256] = bf16(emb[tokens[b][t]]) ----------
__global__ void k_gather(const int* __restrict__ tokens,
                         const float* __restrict__ emb,
                         __hip_bfloat16* __restrict__ xb) {
  int tid = threadIdx.x;
  int row = blockIdx.x * 4 + (tid >> 6);   // 512 blocks -> 2048 rows
  int lane = tid & 63;
  int t = row >> 6, b = row & 63;
  int tok = tokens[b * TLEN + t];
  float4 v = *reinterpret_cast<const float4*>(emb + (size_t)tok * EMBD + lane * 4);
  __hip_bfloat16* d = xb + (size_t)row * EMBD + lane * 4;
  d[0] = __float2bfloat16(v.x);
  d[1] = __float2bfloat16(v.y);
  d[2] = __float2bfloat16(v.z);
  d[3] = __float2bfloat16(v.w);
}

__device__ __forceinline__ void store_agent_u32(unsigned* p, unsigned v) {
  __hip_atomic_store(p, v, __ATOMIC_RELAXED, __HIP_MEMORY_SCOPE_AGENT);
}
__device__ __forceinline__ unsigned load_agent_u32(const unsigned* p) {
  return __hip_atomic_load(p, __ATOMIC_RELAXED, __HIP_MEMORY_SCOPE_AGENT);
}
__device__ __forceinline__ unsigned long long load_agent_u64(const void* p) {
  return __hip_atomic_load((const unsigned long long*)p, __ATOMIC_RELAXED,
                           __HIP_MEMORY_SCOPE_AGENT);
}
__device__ __forceinline__ void store_agent_f32(float* p, float v) {
  __hip_atomic_store(p, v, __ATOMIC_RELAXED, __HIP_MEMORY_SCOPE_AGENT);
}
__device__ __forceinline__ float2 load_agent_f32x2(const float* p) {
  unsigned long long u = load_agent_u64(p);
  float2 f;
  __builtin_memcpy(&f, &u, 8);
  return f;
}
__device__ __forceinline__ unsigned short bf16_bits(float x) {
  __hip_bfloat16 h = __float2bfloat16(x);
  unsigned short u;
  __builtin_memcpy(&u, &h, 2);
  return u;
}

// Two-hop store-based grid barrier (round-7/10 design, best measured).
// Arrival: each block STORES t+1 into its own arrv word (no RMW). Block 0's
// wave 0 polls all 256 words (2 x 8B agent loads/lane + __all), then stores
// 8 per-XCD release lines; other blocks poll their release line only.
// Monotone values -> no reset. Producers' agent stores (h/stats) are drained
// by the preceding __syncthreads (vmcnt 0) before the arrival store issues.
__device__ __forceinline__ void grid_barrier(unsigned* arrv, unsigned* rel,
                                             int t, int j, int tid, int lane) {
  __syncthreads();
  const unsigned want = (unsigned)(t + 1);
  if (j == 0) {
    if (tid < 64) {                      // wave 0
      if (lane == 0) store_agent_u32(arrv, want);
      for (;;) {
        unsigned long long a = load_agent_u64(arrv + 2 * lane);
        unsigned long long b = load_agent_u64(arrv + 128 + 2 * lane);
        bool ok = ((unsigned)a >= want) && ((unsigned)(a >> 32) >= want) &&
                  ((unsigned)b >= want) && ((unsigned)(b >> 32) >= want);
        if (__all(ok)) break;
      }
      if (lane < 8) store_agent_u32(rel + (lane << 4), want);
    }
  } else {
    if (tid == 0) {
      store_agent_u32(arrv + j, want);
      while (load_agent_u32(rel + ((j & 7) << 4)) < want)
        __builtin_amdgcn_s_sleep(1);
    }
  }
  __syncthreads();
}

// ---------------- persistent kernel: all 32 steps ----------------
// Round-10 kernel + ONE change: the K-loop traversal direction alternates
// each step (ping-pong). Per XCD the B working set is 4.7MB > 4MB L2; a
// same-direction cyclic stream thrashes LRU (~0% hits). Reversing per step
// makes the most-recently-touched 4MB hit L2 (~85%), turning the B stream
// from LLC-bound (~55GB/s/CU) into L2-port-bound.
__global__ __launch_bounds__(512, 1) void k_persist(
    const int* __restrict__ tokens,
    const __hip_bfloat16* __restrict__ WhT,   // [8192][2048]
    const __hip_bfloat16* __restrict__ WxT,   // [8192][256]
    const __hip_bfloat16* __restrict__ xb,    // [2048][256] row = t*64+b
    const float* __restrict__ bias,           // [8192]
    __hip_bfloat16* __restrict__ hring,       // [33][64][2048]
    float* __restrict__ stats,                // [2][3][64][128]
    float* __restrict__ out,                  // [64][32][64]
    unsigned* __restrict__ arrv,              // [256]
    unsigned* __restrict__ rel) {             // [8*16]
  const int tid = threadIdx.x;
  const int lane = tid & 63;
  const int wid = tid >> 6;                  // 0..7 = K-split
  const int j = blockIdx.x;                  // physical id (barrier, bounds)
  const int cg = (j & 7) | ((j >> 4) << 3);  // column group 0..127 (swizzled)
  const int rg = (j >> 3) & 1;               // row group 0..1
  const int r0 = rg << 5;                    // first batch row

  __shared__ float racc[8][2][4][4][64];   // [wid][mf][gt][r][lane] 64KB
  __shared__ float spart[TLEN][3];         // deferred bounds partials
  __shared__ float sval[TLEN];

  const int rr = lane & 15;
  const int kg = lane >> 4;                 // 0..3 (K-subgroups of 8)

  // ---- loop-invariant base pointers ----
  const __hip_bfloat16* bBase[4];
#pragma unroll
  for (int gt = 0; gt < 4; ++gt)
    bBase[gt] = WhT + (size_t)((gt << 11) + (cg << 4) + rr) * VOCAB + wid * 256 + kg * 8;
  const __hip_bfloat16* bxBase[4];
#pragma unroll
  for (int gt = 0; gt < 4; ++gt)
    bxBase[gt] = WxT + (size_t)((gt << 11) + (cg << 4) + rr) * EMBD + wid * 32 + kg * 8;

  // ---- epilogue constants: this thread owns cell (rowg, v) ----
  const int m_e = wid >> 2;                 // 0..1
  const int r_e = wid & 3;                  // 0..3
  const int rowg = r0 + m_e * 16 + kg * 4 + r_e;   // global batch row
  const int v = (cg << 4) + rr;             // global vocab col
  float bias_r[4];
#pragma unroll
  for (int gt = 0; gt < 4; ++gt) bias_r[gt] = bias[gt * 2048 + v];
  float c_reg = 0.f;

  for (int t = 0; t < TLEN; ++t) {
    const int par = t & 1;
    const int rev = t & 1;                   // K ping-pong direction
    const __hip_bfloat16* hcur = hring + (size_t)t * (BATCH * VOCAB);
    __hip_bfloat16* hnext = (__hip_bfloat16*)hring + (size_t)(t + 1) * (BATCH * VOCAB);
    const int tnext = (t + 1 < TLEN) ? t + 1 : TLEN - 1;
    const int tok = tokens[rowg * TLEN + tnext];

    // ---- distributed bounds load: waves 0..2 of blocks j<64, 1x8B each ----
    float2 sv;
    const bool do_stat = (t > 0) && (j < BATCH) && (wid < 3);
    if (do_stat)
      sv = load_agent_f32x2(stats + par * 3 * BATCH * NCG +
                            (wid * BATCH + j) * NCG + lane * 2);

    // ---- GEMM: z[32 rows x 64 zcols] over K=2304, 8 waves split K ----
    f32x4 acc[2][4];
#pragma unroll
    for (int mf = 0; mf < 2; ++mf)
#pragma unroll
      for (int gt = 0; gt < 4; ++gt) acc[mf][gt] = (f32x4){0.f, 0.f, 0.f, 0.f};

    const __hip_bfloat16* aBase = hcur + (size_t)(r0 + rr) * VOCAB + wid * 256 + kg * 8;
    const __hip_bfloat16* xBase = xb + (size_t)t * BATCH * EMBD +
                                  (size_t)(r0 + rr) * EMBD + wid * 32 + kg * 8;
    bf16x8 Ar[4][2];
    bf16x8 Br[4][4];
    auto issue = [&](int it) {
      int slot = it & 3;                    // compile-time ring slot
      if (it < 8) {
        int p = rev ? (7 - it) : it;        // ping-pong physical K index
        Ar[slot][0] = *(const bf16x8*)(aBase + p * 32);
        Ar[slot][1] = *(const bf16x8*)(aBase + 16 * VOCAB + p * 32);
#pragma unroll
        for (int gt = 0; gt < 4; ++gt)
          Br[slot][gt] = *(const bf16x8*)(bBase[gt] + p * 32);
      } else {
        Ar[slot][0] = *(const bf16x8*)(xBase);
        Ar[slot][1] = *(const bf16x8*)(xBase + 16 * EMBD);
#pragma unroll
        for (int gt = 0; gt < 4; ++gt)
          Br[slot][gt] = *(const bf16x8*)(bxBase[gt]);
      }
    };

#pragma unroll
    for (int it = 0; it < 4; ++it) issue(it);
#pragma unroll
    for (int it = 0; it < 9; ++it) {
      const int sl = it & 3;
#pragma unroll
      for (int gt = 0; gt < 4; ++gt) {
        acc[0][gt] = __builtin_amdgcn_mfma_f32_16x16x32_bf16(Ar[sl][0], Br[sl][gt], acc[0][gt], 0, 0, 0);
        acc[1][gt] = __builtin_amdgcn_mfma_f32_16x16x32_bf16(Ar[sl][1], Br[sl][gt], acc[1][gt], 0, 0, 0);
      }
      if (it + 4 < 9) issue(it + 4);
    }

    // ---- cross-wave K reduction ----
#pragma unroll
    for (int mf = 0; mf < 2; ++mf)
#pragma unroll
      for (int gt = 0; gt < 4; ++gt)
#pragma unroll
        for (int r = 0; r < 4; ++r) racc[wid][mf][gt][r][lane] = acc[mf][gt][r];
    __syncthreads();

    // ---- deferred bounds partial: reduce sv across wave, park in LDS ----
    if (do_stat) {
      float a = sv.x + sv.y;
#pragma unroll
      for (int mm = 1; mm <= 32; mm <<= 1) a += __shfl_xor(a, mm);
      if (lane == 0) spart[t][wid] = a;
    }

    // ---- epilogue: one cell per thread; all 4 gates from LDS ----
    float z[4];
#pragma unroll
    for (int gt = 0; gt < 4; ++gt) {
      float s = bias_r[gt];
#pragma unroll
      for (int w = 0; w < 8; ++w) s += racc[w][m_e][gt][r_e][lane];
      z[gt] = s;
    }
    float gi = 1.f / (1.f + __expf(-z[0]));
    float gf = 1.f / (1.f + __expf(-z[1]));
    float go = 1.f / (1.f + __expf(-z[3]));
    float cnew = gf * c_reg + gi * tanhf(z[2]);
    float hn = go * tanhf(cnew);
    c_reg = cnew;

    // h store: pack col pairs -> one u32 agent store (LLC) per even lane
    {
      unsigned b0 = bf16_bits(hn);
      unsigned q0 = (unsigned)__shfl_xor((int)b0, 1);
      if (!(rr & 1))
        store_agent_u32((unsigned*)(hnext + rowg * VOCAB + v), b0 | (q0 << 16));
    }

    // stats partials over this block's 16 cols (reduce within 16-lane group)
    float e = __expf(hn);
    float sl = (v < tok) ? e : 0.f;
    float st = (v == tok) ? e : 0.f;
#pragma unroll
    for (int mm = 1; mm <= 8; mm <<= 1) {
      e += __shfl_xor(e, mm);
      sl += __shfl_xor(sl, mm);
      st += __shfl_xor(st, mm);
    }
    if (rr == 0) {
      float* stn = stats + (par ^ 1) * 3 * BATCH * NCG;
      store_agent_f32(&stn[(0 * BATCH + rowg) * NCG + cg], e);
      store_agent_f32(&stn[(1 * BATCH + rowg) * NCG + cg], sl);
      store_agent_f32(&stn[(2 * BATCH + rowg) * NCG + cg], st);
    }

    if (t < TLEN - 1) grid_barrier(arrv, rel, t, j, tid, lane);
  }

  // ---- finalize bounds + write out[j] (blocks j<64 only) ----
  if (j < BATCH) {
    __syncthreads();                       // spart of step 31 visible
    if (tid < TLEN) {
      float val;
      if (tid == 0) {
        int tk = tokens[j * TLEN];
        val = 1.5f * (2.f * tk + 1.f) * (1.f / 2048.f);
      } else {
        float S  = spart[tid][0];
        float SL = spart[tid][1];
        float ST = spart[tid][2];
        val = 1.5f * (2.f * SL + ST) / S;
      }
      sval[tid] = val;
    }
    __syncthreads();
    for (int idx = tid; idx < TLEN * LATD; idx += 512) {
      int tp = idx >> 6, d = idx & 63;
      out[j * TLEN * LATD + idx] = (d < TLEN && d <= tp) ? sval[d] : 1.5f;
    }
  }
}

extern "C" void kernel_launch(void* const* d_in, const int* in_sizes, int n_in,
                              void* d_out, int out_size, void* d_ws, size_t ws_size,
                              hipStream_t stream) {
  (void)in_sizes; (void)n_in; (void)out_size; (void)ws_size;
  const int* tokens = (const int*)d_in[0];
  const float* emb  = (const float*)d_in[1];
  const float* Wx   = (const float*)d_in[2];
  const float* Wh   = (const float*)d_in[3];
  const float* bias = (const float*)d_in[4];
  float* out = (float*)d_out;
  char* ws = (char*)d_ws;

  __hip_bfloat16* WhT = (__hip_bfloat16*)(ws);               // 33,554,432 B
  __hip_bfloat16* WxT = (__hip_bfloat16*)(ws + 33554432);    //  4,194,304 B
  __hip_bfloat16* xb  = (__hip_bfloat16*)(ws + 37748736);    //  1,048,576 B
  __hip_bfloat16* hr  = (__hip_bfloat16*)(ws + 38797312);    //  8,650,752 B (33 slots)
  float* stats        = (float*)(ws + 47448064);             //    196,608 B
  unsigned* arrv      = (unsigned*)(ws + 47644672);          //      1,024 B
  unsigned* rel       = (unsigned*)(ws + 47645696);          //        512 B

  k_init<<<512, 256, 0, stream>>>((ushort*)hr, arrv);
  k_transpose<<<4096, 256, 0, stream>>>(Wh, WhT, 2048);
  k_transpose<<<512, 256, 0, stream>>>(Wx, WxT, 256);
  k_gather<<<512, 256, 0, stream>>>(tokens, emb, xb);
  k_persist<<<NBLK, 512, 0, stream>>>(tokens, WhT, WxT, xb, bias, hr, stats, out, arrv, rel);
}

// Round 13
// 258.562 us; speedup vs baseline: 1.8409x; 1.8409x over previous
//
#include <hip/hip_runtime.h>
#include <hip/hip_bf16.h>

#define VOCAB 2048
#define EMBD  256
#define KTOT  2304
#define LATD  64
#define TLEN  32
#define BATCH 64
#define NBLK  256
#define NCG   128   // column groups (16 vocab cols each); rows split 2-way
#define AROW  2304                 // bytes per a8 row (h[2048] || x[256], fp8)
#define ASLOT (BATCH * AROW)       // bytes per time slot

typedef __attribute__((ext_vector_type(4))) float f32x4;

// ---------------- init: a8 slot0 h-region = 0, barrier = 0 ----------------
__global__ void k_init(unsigned char* __restrict__ a8, unsigned* __restrict__ bar) {
  int i = blockIdx.x * 256 + threadIdx.x;   // grid 512*256 = 131072
  if (i < 32768) {                           // 64 rows x 2048 B of h zeros
    int row = i >> 9;
    *(unsigned*)(a8 + (size_t)row * AROW + ((i & 511) << 2)) = 0u;
  }
  if (i < 384) bar[i] = 0;                   // 256 arrv + 128 rel words
}

// -------- transpose+convert: src[K][8192] f32 -> B8[n][koff+k] fp8*32 --------
__global__ void k_conv(const float* __restrict__ src,
                       unsigned char* __restrict__ dst, int koff) {
  __shared__ unsigned char tile[64][80];     // [n][k], 80 -> 16B-aligned rows
  int k0 = (blockIdx.x >> 7) * 64;
  int n0 = (blockIdx.x & 127) * 64;
  int tid = threadIdx.x;
  {
    int kl = tid >> 2;
    int nq = (tid & 3) << 4;
    const float* s = src + (size_t)(k0 + kl) * 8192 + n0 + nq;
#pragma unroll
    for (int i = 0; i < 4; ++i) {
      float4 v = *reinterpret_cast<const float4*>(s + i * 4);
      unsigned pa = (unsigned)__builtin_amdgcn_cvt_pk_fp8_f32(v.x * 32.f, v.y * 32.f, 0, false);
      unsigned pb = (unsigned)__builtin_amdgcn_cvt_pk_fp8_f32(v.z * 32.f, v.w * 32.f, 0, false);
      tile[nq + i * 4 + 0][kl] = (unsigned char)(pa & 0xFF);
      tile[nq + i * 4 + 1][kl] = (unsigned char)((pa >> 8) & 0xFF);
      tile[nq + i * 4 + 2][kl] = (unsigned char)(pb & 0xFF);
      tile[nq + i * 4 + 3][kl] = (unsigned char)((pb >> 8) & 0xFF);
    }
  }
  __syncthreads();
  {
    int nl = tid >> 2;
    int kq = (tid & 3) << 4;
    *(uint4*)(dst + (size_t)(n0 + nl) * AROW + koff + k0 + kq) =
        *(const uint4*)&tile[nl][kq];
  }
}

// ---- gather: a8[t][b][2048+c] = fp8(emb[tokens[b][t]][c] * 256) ----
__global__ void k_gather(const int* __restrict__ tokens,
                         const float* __restrict__ emb,
                         unsigned char* __restrict__ a8) {
  int tid = threadIdx.x;
  int row = blockIdx.x * 4 + (tid >> 6);   // 512 blocks -> 2048 rows
  int lane = tid & 63;
  int t = row >> 6, b = row & 63;
  int tok = tokens[b * TLEN + t];
  float4 v = *reinterpret_cast<const float4*>(emb + (size_t)tok * EMBD + lane * 4);
  unsigned pa = (unsigned)__builtin_amdgcn_cvt_pk_fp8_f32(v.x * 256.f, v.y * 256.f, 0, false);
  unsigned pb = (unsigned)__builtin_amdgcn_cvt_pk_fp8_f32(v.z * 256.f, v.w * 256.f, 0, false);
  *(unsigned*)(a8 + (size_t)t * ASLOT + (size_t)b * AROW + 2048 + lane * 4) =
      (pa & 0xFFFFu) | (pb << 16);
}

__device__ __forceinline__ void store_agent_u32(unsigned* p, unsigned v) {
  __hip_atomic_store(p, v, __ATOMIC_RELAXED, __HIP_MEMORY_SCOPE_AGENT);
}
__device__ __forceinline__ unsigned load_agent_u32(const unsigned* p) {
  return __hip_atomic_load(p, __ATOMIC_RELAXED, __HIP_MEMORY_SCOPE_AGENT);
}
__device__ __forceinline__ unsigned long long load_agent_u64(const void* p) {
  return __hip_atomic_load((const unsigned long long*)p, __ATOMIC_RELAXED,
                           __HIP_MEMORY_SCOPE_AGENT);
}
__device__ __forceinline__ void store_agent_f32(float* p, float v) {
  __hip_atomic_store(p, v, __ATOMIC_RELAXED, __HIP_MEMORY_SCOPE_AGENT);
}
__device__ __forceinline__ float2 load_agent_f32x2(const float* p) {
  unsigned long long u = load_agent_u64(p);
  float2 f;
  __builtin_memcpy(&f, &u, 8);
  return f;
}

// Two-hop store-based grid barrier (round-7/10 design, best measured).
__device__ __forceinline__ void grid_barrier(unsigned* arrv, unsigned* rel,
                                             int t, int j, int tid, int lane) {
  __syncthreads();
  const unsigned want = (unsigned)(t + 1);
  if (j == 0) {
    if (tid < 64) {                      // wave 0
      if (lane == 0) store_agent_u32(arrv, want);
      for (;;) {
        unsigned long long a = load_agent_u64(arrv + 2 * lane);
        unsigned long long b = load_agent_u64(arrv + 128 + 2 * lane);
        bool ok = ((unsigned)a >= want) && ((unsigned)(a >> 32) >= want) &&
                  ((unsigned)b >= want) && ((unsigned)(b >> 32) >= want);
        if (__all(ok)) break;
      }
      if (lane < 8) store_agent_u32(rel + (lane << 4), want);
    }
  } else {
    if (tid == 0) {
      store_agent_u32(arrv + j, want);
      while (load_agent_u32(rel + ((j & 7) << 4)) < want)
        __builtin_amdgcn_s_sleep(1);
    }
  }
  __syncthreads();
}

// ---------------- persistent kernel: all 32 steps, fp8 GEMM ----------------
// Round-10 structure; GEMM switched to mfma_f32_16x16x32_fp8_fp8 over the
// combined K=2304 fp8 layout (h*256 || x*256) x (W*32) -> z = acc/8192.
// Per-wave B panel = 9 iters x 4 gates x 8B = 72 VGPRs, loaded ONCE before
// the t-loop (B is step-invariant) -> zero weight traffic in the loop.
// A traffic halves to 72KB/block/step.
__global__ __launch_bounds__(512, 1) void k_persist(
    const int* __restrict__ tokens,
    const unsigned char* __restrict__ B8,     // [8192][2304] fp8 (W*32)
    unsigned char* __restrict__ a8,           // [33][64][2304] fp8 (h||x)*256
    const float* __restrict__ bias,           // [8192]
    float* __restrict__ stats,                // [2][3][64][128]
    float* __restrict__ out,                  // [64][32][64]
    unsigned* __restrict__ arrv,              // [256]
    unsigned* __restrict__ rel) {             // [8*16]
  const int tid = threadIdx.x;
  const int lane = tid & 63;
  const int wid = tid >> 6;                  // 0..7 = K-split (288 B each)
  const int j = blockIdx.x;                  // physical id (barrier, bounds)
  const int cg = (j & 7) | ((j >> 4) << 3);  // column group 0..127 (swizzled)
  const int rg = (j >> 3) & 1;               // row group 0..1
  const int r0 = rg << 5;                    // first batch row

  __shared__ float racc[8][2][4][4][64];   // [wid][mf][gt][r][lane] 64KB
  __shared__ float spart[TLEN][3];         // deferred bounds partials
  __shared__ float sval[TLEN];

  const int rr = lane & 15;
  const int kg = lane >> 4;                 // 0..3 (K-subgroups of 8 bytes)

  // ---- B panel resident in VGPRs (72 regs), loaded once ----
  long Bf[9][4];
  {
    const unsigned char* b8B[4];
#pragma unroll
    for (int gt = 0; gt < 4; ++gt)
      b8B[gt] = B8 + (size_t)((gt << 11) + (cg << 4) + rr) * AROW + wid * 288 + kg * 8;
#pragma unroll
    for (int it = 0; it < 9; ++it)
#pragma unroll
      for (int gt = 0; gt < 4; ++gt)
        Bf[it][gt] = *(const long*)(b8B[gt] + it * 32);
  }

  // ---- epilogue constants: this thread owns cell (rowg, v) ----
  const int m_e = wid >> 2;                 // 0..1
  const int r_e = wid & 3;                  // 0..3
  const int rowg = r0 + m_e * 16 + kg * 4 + r_e;   // global batch row
  const int v = (cg << 4) + rr;             // global vocab col
  float bias_r[4];
#pragma unroll
  for (int gt = 0; gt < 4; ++gt) bias_r[gt] = bias[gt * 2048 + v];
  float c_reg = 0.f;

  for (int t = 0; t < TLEN; ++t) {
    const int par = t & 1;
    const unsigned char* a8cur = a8 + (size_t)t * ASLOT;
    unsigned char* a8next = a8 + (size_t)(t + 1) * ASLOT;
    const int tnext = (t + 1 < TLEN) ? t + 1 : TLEN - 1;
    const int tok = tokens[rowg * TLEN + tnext];

    // ---- distributed bounds load: waves 0..2 of blocks j<64, 1x8B each ----
    float2 sv;
    const bool do_stat = (t > 0) && (j < BATCH) && (wid < 3);
    if (do_stat)
      sv = load_agent_f32x2(stats + par * 3 * BATCH * NCG +
                            (wid * BATCH + j) * NCG + lane * 2);

    // ---- GEMM: z[32 rows x 64 zcols] over K=2304 fp8, 8 waves split K ----
    f32x4 acc[2][4];
#pragma unroll
    for (int mf = 0; mf < 2; ++mf)
#pragma unroll
      for (int gt = 0; gt < 4; ++gt) acc[mf][gt] = (f32x4){0.f, 0.f, 0.f, 0.f};

    const unsigned char* aB = a8cur + (size_t)(r0 + rr) * AROW + wid * 288 + kg * 8;
    long Ar[4][2];
    auto issue = [&](int it) {
      int slot = it & 3;
      Ar[slot][0] = *(const long*)(aB + it * 32);
      Ar[slot][1] = *(const long*)(aB + 16 * AROW + it * 32);
    };

#pragma unroll
    for (int it = 0; it < 4; ++it) issue(it);
#pragma unroll
    for (int it = 0; it < 9; ++it) {
      const int sl = it & 3;
#pragma unroll
      for (int gt = 0; gt < 4; ++gt) {
        acc[0][gt] = __builtin_amdgcn_mfma_f32_16x16x32_fp8_fp8(Ar[sl][0], Bf[it][gt], acc[0][gt], 0, 0, 0);
        acc[1][gt] = __builtin_amdgcn_mfma_f32_16x16x32_fp8_fp8(Ar[sl][1], Bf[it][gt], acc[1][gt], 0, 0, 0);
      }
      if (it + 4 < 9) issue(it + 4);
    }

    // ---- cross-wave K reduction ----
#pragma unroll
    for (int mf = 0; mf < 2; ++mf)
#pragma unroll
      for (int gt = 0; gt < 4; ++gt)
#pragma unroll
        for (int r = 0; r < 4; ++r) racc[wid][mf][gt][r][lane] = acc[mf][gt][r];
    __syncthreads();

    // ---- deferred bounds partial: reduce sv across wave, park in LDS ----
    if (do_stat) {
      float a = sv.x + sv.y;
#pragma unroll
      for (int mm = 1; mm <= 32; mm <<= 1) a += __shfl_xor(a, mm);
      if (lane == 0) spart[t][wid] = a;
    }

    // ---- epilogue: one cell per thread; all 4 gates from LDS ----
    float z[4];
#pragma unroll
    for (int gt = 0; gt < 4; ++gt) {
      float s = 0.f;
#pragma unroll
      for (int w = 0; w < 8; ++w) s += racc[w][m_e][gt][r_e][lane];
      z[gt] = s * (1.f / 8192.f) + bias_r[gt];
    }
    float gi = 1.f / (1.f + __expf(-z[0]));
    float gf = 1.f / (1.f + __expf(-z[1]));
    float go = 1.f / (1.f + __expf(-z[3]));
    float cnew = gf * c_reg + gi * tanhf(z[2]);
    float hn = go * tanhf(cnew);
    c_reg = cnew;

    // h store: fp8(hn*256), pack 4 cols -> one u32 agent store per 4 lanes
    {
      float hs = hn * 256.f;
      float hb = __shfl_xor(hs, 1);
      float lo = (rr & 1) ? hb : hs;
      float hi = (rr & 1) ? hs : hb;
      unsigned pk = (unsigned)__builtin_amdgcn_cvt_pk_fp8_f32(lo, hi, 0, false) & 0xFFFFu;
      unsigned pk2 = (unsigned)__shfl_xor((int)pk, 2);
      unsigned word = pk | (pk2 << 16);       // valid on lanes with (rr&3)==0
      if ((rr & 3) == 0)
        store_agent_u32((unsigned*)(a8next + (size_t)rowg * AROW + v), word);
    }

    // stats partials over this block's 16 cols (reduce within 16-lane group)
    float e = __expf(hn);
    float sl = (v < tok) ? e : 0.f;
    float st = (v == tok) ? e : 0.f;
#pragma unroll
    for (int mm = 1; mm <= 8; mm <<= 1) {
      e += __shfl_xor(e, mm);
      sl += __shfl_xor(sl, mm);
      st += __shfl_xor(st, mm);
    }
    if (rr == 0) {
      float* stn = stats + (par ^ 1) * 3 * BATCH * NCG;
      store_agent_f32(&stn[(0 * BATCH + rowg) * NCG + cg], e);
      store_agent_f32(&stn[(1 * BATCH + rowg) * NCG + cg], sl);
      store_agent_f32(&stn[(2 * BATCH + rowg) * NCG + cg], st);
    }

    if (t < TLEN - 1) grid_barrier(arrv, rel, t, j, tid, lane);
  }

  // ---- finalize bounds + write out[j] (blocks j<64 only) ----
  if (j < BATCH) {
    __syncthreads();                       // spart of step 31 visible
    if (tid < TLEN) {
      float val;
      if (tid == 0) {
        int tk = tokens[j * TLEN];
        val = 1.5f * (2.f * tk + 1.f) * (1.f / 2048.f);
      } else {
        float S  = spart[tid][0];
        float SL = spart[tid][1];
        float ST = spart[tid][2];
        val = 1.5f * (2.f * SL + ST) / S;
      }
      sval[tid] = val;
    }
    __syncthreads();
    for (int idx = tid; idx < TLEN * LATD; idx += 512) {
      int tp = idx >> 6, d = idx & 63;
      out[j * TLEN * LATD + idx] = (d < TLEN && d <= tp) ? sval[d] : 1.5f;
    }
  }
}

extern "C" void kernel_launch(void* const* d_in, const int* in_sizes, int n_in,
                              void* d_out, int out_size, void* d_ws, size_t ws_size,
                              hipStream_t stream) {
  (void)in_sizes; (void)n_in; (void)out_size; (void)ws_size;
  const int* tokens = (const int*)d_in[0];
  const float* emb  = (const float*)d_in[1];
  const float* Wx   = (const float*)d_in[2];
  const float* Wh   = (const float*)d_in[3];
  const float* bias = (const float*)d_in[4];
  float* out = (float*)d_out;
  char* ws = (char*)d_ws;

  unsigned char* B8 = (unsigned char*)(ws);                  // 18,874,368 B
  unsigned char* a8 = (unsigned char*)(ws + 18874368);       //  4,866,048 B (33 slots)
  float* stats      = (float*)(ws + 23740416);               //    196,608 B
  unsigned* arrv    = (unsigned*)(ws + 23937024);            //      1,024 B (256 w)
  unsigned* rel     = (unsigned*)(ws + 23938048);            //        512 B

  k_init<<<512, 256, 0, stream>>>(a8, arrv);
  k_conv<<<4096, 256, 0, stream>>>(Wh, B8, 0);      // Wh: K rows 0..2048
  k_conv<<<512, 256, 0, stream>>>(Wx, B8, 2048);    // Wx: K rows 2048..2304
  k_gather<<<512, 256, 0, stream>>>(tokens, emb, a8);
  k_persist<<<NBLK, 512, 0, stream>>>(tokens, B8, a8, bias, stats, out, arrv, rel);
}